// Round 4
// baseline (326.604 us; speedup 1.0000x reference)
//
#include <hip/hip_runtime.h>
#include <hip/hip_bf16.h>

typedef __bf16 bf16;
typedef __attribute__((ext_vector_type(4))) __bf16 bf16x4;
typedef __attribute__((ext_vector_type(8))) __bf16 bf16x8;
typedef __attribute__((ext_vector_type(4))) float f32x4;

#define MFMA16x16x32 __builtin_amdgcn_mfma_f32_16x16x32_bf16

// Problem constants
#define NB 8
#define NC 512
#define NN 4096     // H*W
#define CFG 64

// -------------------- kernel 0: weight prep (fp32 -> bf16, concat) ----------
__global__ __launch_bounds__(256) void k_wprep(
    const float* __restrict__ Wf, const float* __restrict__ bfv,
    const float* __restrict__ Wg, const float* __restrict__ bgv,
    const float* __restrict__ Wh,
    bf16* __restrict__ Wfg, bf16* __restrict__ Whb, float* __restrict__ bfg)
{
    int idx = blockIdx.x * 256 + threadIdx.x;
    if (idx < 32768)       Wfg[idx] = (bf16)Wf[idx];
    else if (idx < 65536)  Wfg[idx] = (bf16)Wg[idx - 32768];
    if (idx < 262144)      Whb[idx] = (bf16)Wh[idx];
    if (idx < 64)          bfg[idx] = bfv[idx];
    else if (idx < 128)    bfg[idx] = bgv[idx - 64];
}

// -------------------- kernel 1: x [B][C][H*W] fp32 -> xT [B][N][C] bf16 -----
// grid (8, 64, 8): blockIdx.x = b  (XCD-affinity: linear%8 == b)
__global__ __launch_bounds__(256) void k_transpose(
    const float* __restrict__ x, bf16* __restrict__ xT)
{
    __shared__ bf16 tile[64][72];
    int b = blockIdx.x, n0 = blockIdx.y * 64, c0 = blockIdx.z * 64;
    int t = threadIdx.x;
    int cl  = t >> 2;
    int seg = (t & 3) * 16;
    const float* src = x + ((size_t)(b * NC + c0 + cl)) * NN + n0 + seg;
#pragma unroll
    for (int u = 0; u < 4; u++) {
        float4 v = ((const float4*)src)[u];
        tile[cl][seg + u*4 + 0] = (bf16)v.x;
        tile[cl][seg + u*4 + 1] = (bf16)v.y;
        tile[cl][seg + u*4 + 2] = (bf16)v.z;
        tile[cl][seg + u*4 + 3] = (bf16)v.w;
    }
    __syncthreads();
    int nl = t >> 2;
    int cs = (t & 3) * 16;
    bf16 buf[16];
#pragma unroll
    for (int u = 0; u < 16; u++) buf[u] = tile[cs + u][nl];
    bf16* dst = xT + ((size_t)(b * NN + n0 + nl)) * NC + c0 + cs;
    ((bf16x8*)dst)[0] = *(bf16x8*)&buf[0];
    ((bf16x8*)dst)[1] = *(bf16x8*)&buf[8];
}

// -------------------- kernel 2a: fg projection GEMM, tiled-fragment output --
// grid (8, 32): blockIdx.x = b
__global__ __launch_bounds__(256) void k_gemm_fg(
    const bf16* __restrict__ xT, const bf16* __restrict__ Wfg,
    const float* __restrict__ bfg,
    bf16* __restrict__ fF, bf16* __restrict__ gF)
{
    int b = blockIdx.x;
    int w = threadIdx.x >> 6, l = threadIdx.x & 63;
    int tile = blockIdx.y * 4 + w;
    int ti = tile >> 1, tj = tile & 1;       // 64 n-tiles x 2 o-tiles
    int lr = l & 15, lq = l >> 4;

    const bf16* Ab = xT + (size_t)b * NN * NC + (size_t)(ti * 64) * NC;
    const bf16* Bb = Wfg + (size_t)(tj * 64) * NC;

    f32x4 acc[4][4] = {};
    for (int k0 = 0; k0 < NC; k0 += 32) {
        bf16x8 a[4], bb[4];
#pragma unroll
        for (int fi = 0; fi < 4; fi++)
            a[fi] = *(const bf16x8*)(Ab + (size_t)(fi*16 + lr) * NC + k0 + lq*8);
#pragma unroll
        for (int fj = 0; fj < 4; fj++)
            bb[fj] = *(const bf16x8*)(Bb + (size_t)(fj*16 + lr) * NC + k0 + lq*8);
#pragma unroll
        for (int fi = 0; fi < 4; fi++)
#pragma unroll
            for (int fj = 0; fj < 4; fj++)
                acc[fi][fj] = MFMA16x16x32(a[fi], bb[fj], acc[fi][fj], 0, 0, 0);
    }
#pragma unroll
    for (int fi = 0; fi < 4; fi++)
#pragma unroll
        for (int fj = 0; fj < 4; fj++)
#pragma unroll
            for (int t = 0; t < 4; t++) {
                int n = ti*64 + fi*16 + lq*4 + t;      // pixel
                int o = tj*64 + fj*16 + lr;            // out channel 0..127
                float v = acc[fi][fj][t] + bfg[o];
                int c = o & 63;
                bf16* dst = (o < 64) ? fF : gF;
                int jt16 = n >> 4, nr = n & 15;
                int ks = c >> 5, lqd = (c >> 3) & 3, e = c & 7;
                size_t off = (((size_t)(b*256 + jt16)*2 + ks)*64 + (lqd*16 + nr))*8 + e;
                dst[off] = (bf16)v;
            }
}

// -------------------- kernel 2b: h projection GEMM, tiled-fragment output ---
// grid (8, 128): blockIdx.x = b
__global__ __launch_bounds__(256) void k_gemm_h(
    const bf16* __restrict__ Whb, const bf16* __restrict__ xT,
    const float* __restrict__ bh,
    bf16* __restrict__ hT)
{
    int b = blockIdx.x;
    int w = threadIdx.x >> 6, l = threadIdx.x & 63;
    int tile = blockIdx.y * 4 + w;
    int ti = tile >> 6, tj = tile & 63;      // 8 c-tiles x 64 j-tiles
    int lr = l & 15, lq = l >> 4;

    const bf16* Ab = Whb + (size_t)(ti * 64) * NC;
    const bf16* Bb = xT + (size_t)b * NN * NC + (size_t)(tj * 64) * NC;

    f32x4 acc[4][4] = {};
    for (int k0 = 0; k0 < NC; k0 += 32) {
        bf16x8 a[4], bb[4];
#pragma unroll
        for (int fi = 0; fi < 4; fi++)
            a[fi] = *(const bf16x8*)(Ab + (size_t)(fi*16 + lr) * NC + k0 + lq*8);
#pragma unroll
        for (int fj = 0; fj < 4; fj++)
            bb[fj] = *(const bf16x8*)(Bb + (size_t)(fj*16 + lr) * NC + k0 + lq*8);
#pragma unroll
        for (int fi = 0; fi < 4; fi++)
#pragma unroll
            for (int fj = 0; fj < 4; fj++)
                acc[fi][fj] = MFMA16x16x32(a[fi], bb[fj], acc[fi][fj], 0, 0, 0);
    }
#pragma unroll
    for (int fi = 0; fi < 4; fi++)
#pragma unroll
        for (int fj = 0; fj < 4; fj++)
#pragma unroll
            for (int t = 0; t < 4; t++) {
                int c = ti*64 + fi*16 + lq*4 + t;
                int j = tj*64 + fj*16 + lr;
                float v = acc[fi][fj][t] + bh[c];
                int jt = j >> 6, ks = (j >> 5) & 1, lqd = (j >> 3) & 3, e = j & 7;
                int ct = c >> 4, crd = c & 15;
                size_t off = ((((size_t)(b*64 + jt)*32 + ct)*2 + ks)*64 + (lqd*16 + crd))*8 + e;
                hT[off] = (bf16)v;
            }
}

// -------------------- kernel 3: fused attention -----------------------------
// grid (8, 64): blockIdx.x = b (XCD-affinity), blockIdx.y = i-tile.
// Per iter: S(jt+1) -> buf nxt (f loaded at top), PV(jt) from buf cur,
// l-sum accumulated in S phase from float exp values.
__global__ __launch_bounds__(512, 4) void k_attn(
    const bf16* __restrict__ fF, const bf16* __restrict__ gF,
    const bf16* __restrict__ hT, const float* __restrict__ x,
    const float* __restrict__ gammap, float* __restrict__ out)
{
    __shared__ alignas(16) bf16 Pl[2][4][2][64][8];   // 16 KB, A-frag layout
    __shared__ float lpart[4][2][16];
    __shared__ alignas(16) float linv[64];

    int b  = blockIdx.x;
    int i0 = blockIdx.y * 64;
    int w = threadIdx.x >> 6, l = threadIdx.x & 63;
    int lr = l & 15, lq = l >> 4;

    float gamma = *gammap;
    int fi_s = w >> 1;     // i-subtile this wave computes in S
    int ks_s = w & 1;      // j32-block (PV k-block) this wave computes

    bf16* Pf = &Pl[0][0][0][0][0];
    // S-output write offset (elems) for fj=0; fj=1 adds 256.
    int wrA = ((fi_s*2 + ks_s)*64 + (lq >> 1)*16 + lr)*8 + (lq & 1)*4;

    // g B-fragments, hoisted (2 channel-halves)
    const bf16* gbase = gF + ((size_t)(b*256 + (i0 >> 4) + fi_s)*2)*512 + (size_t)l*8;
    bf16x8 bg0 = *(const bf16x8*)(gbase);
    bf16x8 bg1 = *(const bf16x8*)(gbase + 512);

    const bf16* fb0 = fF + (size_t)b*256*2*512 + (size_t)l*8;
    const bf16* hb0 = hT + (size_t)b*64*32*2*512 + (size_t)(w*4)*2*512 + (size_t)l*8;

    f32x4 oacc[4][4] = {};
    float lsum = 0.f;

    // ---- prologue: S(0) -> buf 0 (l-sum counted) ----
    {
        const bf16* fb = fb0 + (size_t)(0*4 + ks_s*2)*1024;
        bf16x8 af00 = *(const bf16x8*)(fb);
        bf16x8 af01 = *(const bf16x8*)(fb + 512);
        bf16x8 af10 = *(const bf16x8*)(fb + 1024);
        bf16x8 af11 = *(const bf16x8*)(fb + 1536);
        f32x4 s0 = {}, s1 = {};
        s0 = MFMA16x16x32(af00, bg0, s0, 0, 0, 0);
        s0 = MFMA16x16x32(af01, bg1, s0, 0, 0, 0);
        s1 = MFMA16x16x32(af10, bg0, s1, 0, 0, 0);
        s1 = MFMA16x16x32(af11, bg1, s1, 0, 0, 0);
        bf16x4 p0, p1;
#pragma unroll
        for (int t = 0; t < 4; t++) {
            float e0 = __expf(s0[t]), e1 = __expf(s1[t]);
            lsum += e0 + e1;
            p0[t] = (bf16)e0;
            p1[t] = (bf16)e1;
        }
        *(bf16x4*)(Pf + wrA)       = p0;
        *(bf16x4*)(Pf + wrA + 256) = p1;
    }
    __syncthreads();

    for (int jt = 0; jt < 64; jt++) {
        int cur = jt & 1, nxt = cur ^ 1;
        int jn = (jt + 1) & 63;

        // ---- issue f(jt+1) then h(jt) loads ----
        const bf16* fb = fb0 + (size_t)(jn*4 + ks_s*2)*1024;
        bf16x8 af00 = *(const bf16x8*)(fb);
        bf16x8 af01 = *(const bf16x8*)(fb + 512);
        bf16x8 af10 = *(const bf16x8*)(fb + 1024);
        bf16x8 af11 = *(const bf16x8*)(fb + 1536);

        const bf16* hb = hb0 + (size_t)jt * 32768;
        bf16x8 bh[4][2];
#pragma unroll
        for (int fc = 0; fc < 4; fc++) {
            bh[fc][0] = *(const bf16x8*)(hb + (fc*2 + 0)*512);
            bh[fc][1] = *(const bf16x8*)(hb + (fc*2 + 1)*512);
        }

        // ---- S(jt+1) -> Pl[nxt] (redundant at jt=63: skip l-sum) ----
        {
            f32x4 s0 = {}, s1 = {};
            s0 = MFMA16x16x32(af00, bg0, s0, 0, 0, 0);
            s0 = MFMA16x16x32(af01, bg1, s0, 0, 0, 0);
            s1 = MFMA16x16x32(af10, bg0, s1, 0, 0, 0);
            s1 = MFMA16x16x32(af11, bg1, s1, 0, 0, 0);
            bf16x4 p0, p1;
            if (jt < 63) {
#pragma unroll
                for (int t = 0; t < 4; t++) {
                    float e0 = __expf(s0[t]), e1 = __expf(s1[t]);
                    lsum += e0 + e1;
                    p0[t] = (bf16)e0;
                    p1[t] = (bf16)e1;
                }
            } else {
#pragma unroll
                for (int t = 0; t < 4; t++) {
                    p0[t] = (bf16)__expf(s0[t]);
                    p1[t] = (bf16)__expf(s1[t]);
                }
            }
            *(bf16x4*)(Pf + nxt*4096 + wrA)       = p0;
            *(bf16x4*)(Pf + nxt*4096 + wrA + 256) = p1;
        }

        // ---- PV(jt) from Pl[cur] ----
        const bf16* Pr = Pf + cur*4096 + l*8;
        __builtin_amdgcn_s_setprio(1);
#pragma unroll
        for (int fi = 0; fi < 4; fi++) {
            bf16x8 ap0 = *(const bf16x8*)(Pr + (fi*2 + 0)*512);
            bf16x8 ap1 = *(const bf16x8*)(Pr + (fi*2 + 1)*512);
#pragma unroll
            for (int fc = 0; fc < 4; fc++) {
                oacc[fi][fc] = MFMA16x16x32(ap0, bh[fc][0], oacc[fi][fc], 0, 0, 0);
                oacc[fi][fc] = MFMA16x16x32(ap1, bh[fc][1], oacc[fi][fc], 0, 0, 0);
            }
        }
        __builtin_amdgcn_s_setprio(0);

        __syncthreads();
    }

    // ---- l reduction: per-wave partials -> LDS -> linv ----
    lsum += __shfl_xor(lsum, 16, 64);
    lsum += __shfl_xor(lsum, 32, 64);
    if (lq == 0) lpart[fi_s][ks_s][lr] = lsum;
    __syncthreads();
    if (threadIdx.x < 64) {
        int i = threadIdx.x;
        linv[i] = 1.0f / (lpart[i >> 4][0][i & 15] + lpart[i >> 4][1][i & 15]);
    }
    __syncthreads();

    // ---- epilogue: out = gamma * O/l + x ----
    int cw = w * 64;
    const float* xb = x + (size_t)b * NC * NN;
    float* ob = out + (size_t)b * NC * NN;
#pragma unroll
    for (int fi = 0; fi < 4; fi++) {
        f32x4 li = *(const f32x4*)&linv[fi*16 + lq*4];
#pragma unroll
        for (int fc = 0; fc < 4; fc++) {
            int c = cw + fc*16 + lr;
            size_t base = (size_t)c * NN + i0 + fi*16 + lq*4;
            float4 xv = *(const float4*)(xb + base);
            float4 ov;
            ov.x = gamma * oacc[fi][fc][0] * li[0] + xv.x;
            ov.y = gamma * oacc[fi][fc][1] * li[1] + xv.y;
            ov.z = gamma * oacc[fi][fc][2] * li[2] + xv.z;
            ov.w = gamma * oacc[fi][fc][3] * li[3] + xv.w;
            *(float4*)(ob + base) = ov;
        }
    }
}

// -------------------- launcher ----------------------------------------------
extern "C" void kernel_launch(void* const* d_in, const int* in_sizes, int n_in,
                              void* d_out, int out_size, void* d_ws, size_t ws_size,
                              hipStream_t stream)
{
    const float* x     = (const float*)d_in[0];
    const float* Wf    = (const float*)d_in[1];
    const float* bf_   = (const float*)d_in[2];
    const float* Wg    = (const float*)d_in[3];
    const float* bg_   = (const float*)d_in[4];
    const float* Wh    = (const float*)d_in[5];
    const float* bh_   = (const float*)d_in[6];
    const float* gamma = (const float*)d_in[7];
    float* out = (float*)d_out;

    char* ws = (char*)d_ws;
    bf16*  xT  = (bf16*)(ws);
    bf16*  hT  = (bf16*)(ws + 33554432);
    bf16*  fF  = (bf16*)(ws + 67108864);
    bf16*  gF  = (bf16*)(ws + 71303168);
    bf16*  Wfg = (bf16*)(ws + 75497472);
    bf16*  Whb = (bf16*)(ws + 75628544);
    float* bfg = (float*)(ws + 76152832);

    k_wprep<<<dim3(1024), dim3(256), 0, stream>>>(Wf, bf_, Wg, bg_, Wh, Wfg, Whb, bfg);
    k_transpose<<<dim3(8, 64, 8), dim3(256), 0, stream>>>(x, xT);
    k_gemm_fg<<<dim3(8, 32), dim3(256), 0, stream>>>(xT, Wfg, bfg, fF, gF);
    k_gemm_h<<<dim3(8, 128), dim3(256), 0, stream>>>(Whb, xT, bh_, hT);
    k_attn<<<dim3(8, 64), dim3(512), 0, stream>>>(fF, gF, hT, x, gamma, out);
}

// Round 5
// 272.404 us; speedup vs baseline: 1.1990x; 1.1990x over previous
//
#include <hip/hip_runtime.h>
#include <hip/hip_bf16.h>

typedef __bf16 bf16;
typedef __attribute__((ext_vector_type(4))) __bf16 bf16x4;
typedef __attribute__((ext_vector_type(8))) __bf16 bf16x8;
typedef __attribute__((ext_vector_type(4))) float f32x4;

#define MFMA16x16x32 __builtin_amdgcn_mfma_f32_16x16x32_bf16

// Problem constants
#define NB 8
#define NC 512
#define NN 4096     // H*W
#define CFG 64

// -------------------- kernel 0: weight prep (fp32 -> bf16, concat) ----------
__global__ __launch_bounds__(256) void k_wprep(
    const float* __restrict__ Wf, const float* __restrict__ bfv,
    const float* __restrict__ Wg, const float* __restrict__ bgv,
    const float* __restrict__ Wh,
    bf16* __restrict__ Wfg, bf16* __restrict__ Whb, float* __restrict__ bfg)
{
    int idx = blockIdx.x * 256 + threadIdx.x;
    if (idx < 32768)       Wfg[idx] = (bf16)Wf[idx];
    else if (idx < 65536)  Wfg[idx] = (bf16)Wg[idx - 32768];
    if (idx < 262144)      Whb[idx] = (bf16)Wh[idx];
    if (idx < 64)          bfg[idx] = bfv[idx];
    else if (idx < 128)    bfg[idx] = bgv[idx - 64];
}

// -------------------- kernel 1: x [B][C][H*W] fp32 -> xT [B][N][C] bf16 -----
// grid (8, 64, 8): blockIdx.x = b  (XCD-affinity: linear%8 == b)
__global__ __launch_bounds__(256) void k_transpose(
    const float* __restrict__ x, bf16* __restrict__ xT)
{
    __shared__ bf16 tile[64][72];
    int b = blockIdx.x, n0 = blockIdx.y * 64, c0 = blockIdx.z * 64;
    int t = threadIdx.x;
    int cl  = t >> 2;
    int seg = (t & 3) * 16;
    const float* src = x + ((size_t)(b * NC + c0 + cl)) * NN + n0 + seg;
#pragma unroll
    for (int u = 0; u < 4; u++) {
        float4 v = ((const float4*)src)[u];
        tile[cl][seg + u*4 + 0] = (bf16)v.x;
        tile[cl][seg + u*4 + 1] = (bf16)v.y;
        tile[cl][seg + u*4 + 2] = (bf16)v.z;
        tile[cl][seg + u*4 + 3] = (bf16)v.w;
    }
    __syncthreads();
    int nl = t >> 2;
    int cs = (t & 3) * 16;
    bf16 buf[16];
#pragma unroll
    for (int u = 0; u < 16; u++) buf[u] = tile[cs + u][nl];
    bf16* dst = xT + ((size_t)(b * NN + n0 + nl)) * NC + c0 + cs;
    ((bf16x8*)dst)[0] = *(bf16x8*)&buf[0];
    ((bf16x8*)dst)[1] = *(bf16x8*)&buf[8];
}

// -------------------- kernel 2a: fg projection GEMM, tiled-fragment output --
// grid (8, 32): blockIdx.x = b
__global__ __launch_bounds__(256) void k_gemm_fg(
    const bf16* __restrict__ xT, const bf16* __restrict__ Wfg,
    const float* __restrict__ bfg,
    bf16* __restrict__ fF, bf16* __restrict__ gF)
{
    int b = blockIdx.x;
    int w = threadIdx.x >> 6, l = threadIdx.x & 63;
    int tile = blockIdx.y * 4 + w;
    int ti = tile >> 1, tj = tile & 1;       // 64 n-tiles x 2 o-tiles
    int lr = l & 15, lq = l >> 4;

    const bf16* Ab = xT + (size_t)b * NN * NC + (size_t)(ti * 64) * NC;
    const bf16* Bb = Wfg + (size_t)(tj * 64) * NC;

    f32x4 acc[4][4] = {};
    for (int k0 = 0; k0 < NC; k0 += 32) {
        bf16x8 a[4], bb[4];
#pragma unroll
        for (int fi = 0; fi < 4; fi++)
            a[fi] = *(const bf16x8*)(Ab + (size_t)(fi*16 + lr) * NC + k0 + lq*8);
#pragma unroll
        for (int fj = 0; fj < 4; fj++)
            bb[fj] = *(const bf16x8*)(Bb + (size_t)(fj*16 + lr) * NC + k0 + lq*8);
#pragma unroll
        for (int fi = 0; fi < 4; fi++)
#pragma unroll
            for (int fj = 0; fj < 4; fj++)
                acc[fi][fj] = MFMA16x16x32(a[fi], bb[fj], acc[fi][fj], 0, 0, 0);
    }
#pragma unroll
    for (int fi = 0; fi < 4; fi++)
#pragma unroll
        for (int fj = 0; fj < 4; fj++)
#pragma unroll
            for (int t = 0; t < 4; t++) {
                int n = ti*64 + fi*16 + lq*4 + t;      // pixel
                int o = tj*64 + fj*16 + lr;            // out channel 0..127
                float v = acc[fi][fj][t] + bfg[o];
                int c = o & 63;
                bf16* dst = (o < 64) ? fF : gF;
                int jt16 = n >> 4, nr = n & 15;
                int ks = c >> 5, lqd = (c >> 3) & 3, e = c & 7;
                size_t off = (((size_t)(b*256 + jt16)*2 + ks)*64 + (lqd*16 + nr))*8 + e;
                dst[off] = (bf16)v;
            }
}

// -------------------- kernel 2b: h projection GEMM, tiled-fragment output ---
// grid (8, 128): blockIdx.x = b
__global__ __launch_bounds__(256) void k_gemm_h(
    const bf16* __restrict__ Whb, const bf16* __restrict__ xT,
    const float* __restrict__ bh,
    bf16* __restrict__ hT)
{
    int b = blockIdx.x;
    int w = threadIdx.x >> 6, l = threadIdx.x & 63;
    int tile = blockIdx.y * 4 + w;
    int ti = tile >> 6, tj = tile & 63;      // 8 c-tiles x 64 j-tiles
    int lr = l & 15, lq = l >> 4;

    const bf16* Ab = Whb + (size_t)(ti * 64) * NC;
    const bf16* Bb = xT + (size_t)b * NN * NC + (size_t)(tj * 64) * NC;

    f32x4 acc[4][4] = {};
    for (int k0 = 0; k0 < NC; k0 += 32) {
        bf16x8 a[4], bb[4];
#pragma unroll
        for (int fi = 0; fi < 4; fi++)
            a[fi] = *(const bf16x8*)(Ab + (size_t)(fi*16 + lr) * NC + k0 + lq*8);
#pragma unroll
        for (int fj = 0; fj < 4; fj++)
            bb[fj] = *(const bf16x8*)(Bb + (size_t)(fj*16 + lr) * NC + k0 + lq*8);
#pragma unroll
        for (int fi = 0; fi < 4; fi++)
#pragma unroll
            for (int fj = 0; fj < 4; fj++)
                acc[fi][fj] = MFMA16x16x32(a[fi], bb[fj], acc[fi][fj], 0, 0, 0);
    }
#pragma unroll
    for (int fi = 0; fi < 4; fi++)
#pragma unroll
        for (int fj = 0; fj < 4; fj++)
#pragma unroll
            for (int t = 0; t < 4; t++) {
                int c = ti*64 + fi*16 + lq*4 + t;
                int j = tj*64 + fj*16 + lr;
                float v = acc[fi][fj][t] + bh[c];
                int jt = j >> 6, ks = (j >> 5) & 1, lqd = (j >> 3) & 3, e = j & 7;
                int ct = c >> 4, crd = c & 15;
                size_t off = ((((size_t)(b*64 + jt)*32 + ct)*2 + ks)*64 + (lqd*16 + crd))*8 + e;
                hT[off] = (bf16)v;
            }
}

// -------------------- kernel 3: fused attention -----------------------------
// grid (8, 64): blockIdx.x = b (XCD-affinity). R3 schedule: per iter
// {issue h(jt), PV(jt) from P[cur], S(jt+1)->P[nxt] (self-contained), barrier}.
// l-sum accumulated in S phase from float exp values (all waves).
__global__ __launch_bounds__(512, 4) void k_attn(
    const bf16* __restrict__ fF, const bf16* __restrict__ gF,
    const bf16* __restrict__ hT, const float* __restrict__ x,
    const float* __restrict__ gammap, float* __restrict__ out)
{
    __shared__ alignas(16) bf16 Pl[2][4][2][64][8];   // 16 KB, A-frag layout
    __shared__ float lpart[4][2][16];
    __shared__ alignas(16) float linv[64];

    int b  = blockIdx.x;
    int i0 = blockIdx.y * 64;
    int w = threadIdx.x >> 6, l = threadIdx.x & 63;
    int lr = l & 15, lq = l >> 4;

    float gamma = *gammap;
    int fi_s = w >> 1;     // i-subtile this wave computes in S
    int ks_s = w & 1;      // j32-block (PV k-block) this wave computes

    bf16* Pf = &Pl[0][0][0][0][0];
    // S-output write offset (elems) for fj=0; fj=1 adds 256.
    int wrA = ((fi_s*2 + ks_s)*64 + (lq >> 1)*16 + lr)*8 + (lq & 1)*4;

    // g B-fragments, hoisted (2 channel-halves)
    const bf16* gbase = gF + ((size_t)(b*256 + (i0 >> 4) + fi_s)*2)*512 + (size_t)l*8;
    bf16x8 bg0 = *(const bf16x8*)(gbase);
    bf16x8 bg1 = *(const bf16x8*)(gbase + 512);

    const bf16* fb0 = fF + (size_t)b*256*2*512 + (size_t)l*8;
    const bf16* hb0 = hT + (size_t)b*64*32*2*512 + (size_t)(w*4)*2*512 + (size_t)l*8;

    f32x4 oacc[4][4] = {};
    float lsum = 0.f;

    // ---- S for j-tile jn -> Pl[buf]; l-sum counted iff COUNT ----
#define S_STEP(jn, buf, COUNT)                                                 \
    {                                                                          \
        const bf16* fb = fb0 + (size_t)((jn)*4 + ks_s*2)*1024;                 \
        bf16x8 af00 = *(const bf16x8*)(fb);                                    \
        bf16x8 af01 = *(const bf16x8*)(fb + 512);                              \
        bf16x8 af10 = *(const bf16x8*)(fb + 1024);                             \
        bf16x8 af11 = *(const bf16x8*)(fb + 1536);                             \
        f32x4 s0 = {}, s1 = {};                                                \
        s0 = MFMA16x16x32(af00, bg0, s0, 0, 0, 0);                             \
        s0 = MFMA16x16x32(af01, bg1, s0, 0, 0, 0);                             \
        s1 = MFMA16x16x32(af10, bg0, s1, 0, 0, 0);                             \
        s1 = MFMA16x16x32(af11, bg1, s1, 0, 0, 0);                             \
        bf16x4 p0, p1;                                                         \
        if (COUNT) {                                                           \
            _Pragma("unroll")                                                  \
            for (int t = 0; t < 4; t++) {                                      \
                float e0 = __expf(s0[t]), e1 = __expf(s1[t]);                  \
                lsum += e0 + e1;                                               \
                p0[t] = (bf16)e0;                                              \
                p1[t] = (bf16)e1;                                              \
            }                                                                  \
        } else {                                                               \
            _Pragma("unroll")                                                  \
            for (int t = 0; t < 4; t++) {                                      \
                p0[t] = (bf16)__expf(s0[t]);                                   \
                p1[t] = (bf16)__expf(s1[t]);                                   \
            }                                                                  \
        }                                                                      \
        *(bf16x4*)(Pf + (buf)*4096 + wrA)       = p0;                          \
        *(bf16x4*)(Pf + (buf)*4096 + wrA + 256) = p1;                          \
    }

    // prologue: S(0) -> buf 0
    S_STEP(0, 0, 1)
    __syncthreads();

    for (int jt = 0; jt < 64; jt++) {
        int cur = jt & 1, nxt = cur ^ 1;
        int jn = (jt + 1) & 63;

        // ---- issue h(jt) loads ----
        const bf16* hb = hb0 + (size_t)jt * 32768;
        bf16x8 bh[4][2];
#pragma unroll
        for (int fc = 0; fc < 4; fc++) {
            bh[fc][0] = *(const bf16x8*)(hb + (fc*2 + 0)*512);
            bh[fc][1] = *(const bf16x8*)(hb + (fc*2 + 1)*512);
        }

        // ---- PV(jt) from Pl[cur] ----
        const bf16* Pr = Pf + cur*4096 + l*8;
        __builtin_amdgcn_s_setprio(1);
#pragma unroll
        for (int fi = 0; fi < 4; fi++) {
            bf16x8 ap0 = *(const bf16x8*)(Pr + (fi*2 + 0)*512);
            bf16x8 ap1 = *(const bf16x8*)(Pr + (fi*2 + 1)*512);
#pragma unroll
            for (int fc = 0; fc < 4; fc++) {
                oacc[fi][fc] = MFMA16x16x32(ap0, bh[fc][0], oacc[fi][fc], 0, 0, 0);
                oacc[fi][fc] = MFMA16x16x32(ap1, bh[fc][1], oacc[fi][fc], 0, 0, 0);
            }
        }
        __builtin_amdgcn_s_setprio(0);

        // ---- S(jt+1) -> Pl[nxt] (redundant at jt=63: skip l-sum) ----
        S_STEP(jn, nxt, (jt < 63))

        __syncthreads();
    }
#undef S_STEP

    // ---- l reduction: per-wave partials -> LDS -> linv ----
    lsum += __shfl_xor(lsum, 16, 64);
    lsum += __shfl_xor(lsum, 32, 64);
    if (lq == 0) lpart[fi_s][ks_s][lr] = lsum;
    __syncthreads();
    if (threadIdx.x < 64) {
        int i = threadIdx.x;
        linv[i] = 1.0f / (lpart[i >> 4][0][i & 15] + lpart[i >> 4][1][i & 15]);
    }
    __syncthreads();

    // ---- epilogue: out = gamma * O/l + x ----
    int cw = w * 64;
    const float* xb = x + (size_t)b * NC * NN;
    float* ob = out + (size_t)b * NC * NN;
#pragma unroll
    for (int fi = 0; fi < 4; fi++) {
        f32x4 li = *(const f32x4*)&linv[fi*16 + lq*4];
#pragma unroll
        for (int fc = 0; fc < 4; fc++) {
            int c = cw + fc*16 + lr;
            size_t base = (size_t)c * NN + i0 + fi*16 + lq*4;
            float4 xv = *(const float4*)(xb + base);
            float4 ov;
            ov.x = gamma * oacc[fi][fc][0] * li[0] + xv.x;
            ov.y = gamma * oacc[fi][fc][1] * li[1] + xv.y;
            ov.z = gamma * oacc[fi][fc][2] * li[2] + xv.z;
            ov.w = gamma * oacc[fi][fc][3] * li[3] + xv.w;
            *(float4*)(ob + base) = ov;
        }
    }
}

// -------------------- launcher ----------------------------------------------
extern "C" void kernel_launch(void* const* d_in, const int* in_sizes, int n_in,
                              void* d_out, int out_size, void* d_ws, size_t ws_size,
                              hipStream_t stream)
{
    const float* x     = (const float*)d_in[0];
    const float* Wf    = (const float*)d_in[1];
    const float* bf_   = (const float*)d_in[2];
    const float* Wg    = (const float*)d_in[3];
    const float* bg_   = (const float*)d_in[4];
    const float* Wh    = (const float*)d_in[5];
    const float* bh_   = (const float*)d_in[6];
    const float* gamma = (const float*)d_in[7];
    float* out = (float*)d_out;

    char* ws = (char*)d_ws;
    bf16*  xT  = (bf16*)(ws);
    bf16*  hT  = (bf16*)(ws + 33554432);
    bf16*  fF  = (bf16*)(ws + 67108864);
    bf16*  gF  = (bf16*)(ws + 71303168);
    bf16*  Wfg = (bf16*)(ws + 75497472);
    bf16*  Whb = (bf16*)(ws + 75628544);
    float* bfg = (float*)(ws + 76152832);

    k_wprep<<<dim3(1024), dim3(256), 0, stream>>>(Wf, bf_, Wg, bg_, Wh, Wfg, Whb, bfg);
    k_transpose<<<dim3(8, 64, 8), dim3(256), 0, stream>>>(x, xT);
    k_gemm_fg<<<dim3(8, 32), dim3(256), 0, stream>>>(xT, Wfg, bfg, fF, gF);
    k_gemm_h<<<dim3(8, 128), dim3(256), 0, stream>>>(Whb, xT, bh_, hT);
    k_attn<<<dim3(8, 64), dim3(512), 0, stream>>>(fF, gF, hT, x, gamma, out);
}

// Round 6
// 262.135 us; speedup vs baseline: 1.2459x; 1.0392x over previous
//
#include <hip/hip_runtime.h>
#include <hip/hip_bf16.h>

typedef __bf16 bf16;
typedef __attribute__((ext_vector_type(4))) __bf16 bf16x4;
typedef __attribute__((ext_vector_type(8))) __bf16 bf16x8;
typedef __attribute__((ext_vector_type(4))) float f32x4;

#define MFMA16x16x32 __builtin_amdgcn_mfma_f32_16x16x32_bf16

// Problem constants
#define NB 8
#define NC 512
#define NN 4096     // H*W
#define CFG 64

// -------------------- kernel 0: weight prep (fp32 -> bf16, concat) ----------
__global__ __launch_bounds__(256) void k_wprep(
    const float* __restrict__ Wf, const float* __restrict__ bfv,
    const float* __restrict__ Wg, const float* __restrict__ bgv,
    const float* __restrict__ Wh,
    bf16* __restrict__ Wfg, bf16* __restrict__ Whb, float* __restrict__ bfg)
{
    int idx = blockIdx.x * 256 + threadIdx.x;
    if (idx < 32768)       Wfg[idx] = (bf16)Wf[idx];
    else if (idx < 65536)  Wfg[idx] = (bf16)Wg[idx - 32768];
    if (idx < 262144)      Whb[idx] = (bf16)Wh[idx];
    if (idx < 64)          bfg[idx] = bfv[idx];
    else if (idx < 128)    bfg[idx] = bgv[idx - 64];
}

// -------------------- kernel 1: x [B][C][H*W] fp32 -> xT [B][N][C] bf16 -----
// grid (8, 64, 8): blockIdx.x = b  (XCD-affinity: linear%8 == b)
__global__ __launch_bounds__(256) void k_transpose(
    const float* __restrict__ x, bf16* __restrict__ xT)
{
    __shared__ bf16 tile[64][72];
    int b = blockIdx.x, n0 = blockIdx.y * 64, c0 = blockIdx.z * 64;
    int t = threadIdx.x;
    int cl  = t >> 2;
    int seg = (t & 3) * 16;
    const float* src = x + ((size_t)(b * NC + c0 + cl)) * NN + n0 + seg;
#pragma unroll
    for (int u = 0; u < 4; u++) {
        float4 v = ((const float4*)src)[u];
        tile[cl][seg + u*4 + 0] = (bf16)v.x;
        tile[cl][seg + u*4 + 1] = (bf16)v.y;
        tile[cl][seg + u*4 + 2] = (bf16)v.z;
        tile[cl][seg + u*4 + 3] = (bf16)v.w;
    }
    __syncthreads();
    int nl = t >> 2;
    int cs = (t & 3) * 16;
    bf16 buf[16];
#pragma unroll
    for (int u = 0; u < 16; u++) buf[u] = tile[cs + u][nl];
    bf16* dst = xT + ((size_t)(b * NN + n0 + nl)) * NC + c0 + cs;
    ((bf16x8*)dst)[0] = *(bf16x8*)&buf[0];
    ((bf16x8*)dst)[1] = *(bf16x8*)&buf[8];
}

// -------------------- kernel 2: fused fg+h projection GEMMs ----------------
// grid (8, 160): blockIdx.y < 32 -> fg tiles, else h tiles.
__global__ __launch_bounds__(256) void k_proj(
    const bf16* __restrict__ xT, const bf16* __restrict__ Wfg,
    const float* __restrict__ bfg, const bf16* __restrict__ Whb,
    const float* __restrict__ bh,
    bf16* __restrict__ fF, bf16* __restrict__ gF, bf16* __restrict__ hT)
{
    int b = blockIdx.x;
    int w = threadIdx.x >> 6, l = threadIdx.x & 63;
    int lr = l & 15, lq = l >> 4;

    if (blockIdx.y < 32) {
        // ---------------- fg: D[n][o] = xT[n][:] . Wfg[o][:] + bfg[o] -------
        int tile = blockIdx.y * 4 + w;
        int ti = tile >> 1, tj = tile & 1;       // 64 n-tiles x 2 o-tiles

        const bf16* Ab = xT + (size_t)b * NN * NC + (size_t)(ti * 64) * NC;
        const bf16* Bb = Wfg + (size_t)(tj * 64) * NC;

        f32x4 acc[4][4] = {};
        for (int k0 = 0; k0 < NC; k0 += 32) {
            bf16x8 a[4], bb[4];
#pragma unroll
            for (int fi = 0; fi < 4; fi++)
                a[fi] = *(const bf16x8*)(Ab + (size_t)(fi*16 + lr) * NC + k0 + lq*8);
#pragma unroll
            for (int fj = 0; fj < 4; fj++)
                bb[fj] = *(const bf16x8*)(Bb + (size_t)(fj*16 + lr) * NC + k0 + lq*8);
#pragma unroll
            for (int fi = 0; fi < 4; fi++)
#pragma unroll
                for (int fj = 0; fj < 4; fj++)
                    acc[fi][fj] = MFMA16x16x32(a[fi], bb[fj], acc[fi][fj], 0, 0, 0);
        }
#pragma unroll
        for (int fi = 0; fi < 4; fi++)
#pragma unroll
            for (int fj = 0; fj < 4; fj++)
#pragma unroll
                for (int t = 0; t < 4; t++) {
                    int n = ti*64 + fi*16 + lq*4 + t;      // pixel
                    int o = tj*64 + fj*16 + lr;            // out channel 0..127
                    float v = acc[fi][fj][t] + bfg[o];
                    int c = o & 63;
                    bf16* dst = (o < 64) ? fF : gF;
                    int jt16 = n >> 4, nr = n & 15;
                    int ks = c >> 5, lqd = (c >> 3) & 3, e = c & 7;
                    size_t off = (((size_t)(b*256 + jt16)*2 + ks)*64 + (lqd*16 + nr))*8 + e;
                    dst[off] = (bf16)v;
                }
    } else {
        // ---------------- h: D[c][j] = Whb[c][:] . xT[j][:] + bh[c] ---------
        int tile = (blockIdx.y - 32) * 4 + w;
        int ti = tile >> 6, tj = tile & 63;      // 8 c-tiles x 64 j-tiles

        const bf16* Ab = Whb + (size_t)(ti * 64) * NC;
        const bf16* Bb = xT + (size_t)b * NN * NC + (size_t)(tj * 64) * NC;

        f32x4 acc[4][4] = {};
        for (int k0 = 0; k0 < NC; k0 += 32) {
            bf16x8 a[4], bb[4];
#pragma unroll
            for (int fi = 0; fi < 4; fi++)
                a[fi] = *(const bf16x8*)(Ab + (size_t)(fi*16 + lr) * NC + k0 + lq*8);
#pragma unroll
            for (int fj = 0; fj < 4; fj++)
                bb[fj] = *(const bf16x8*)(Bb + (size_t)(fj*16 + lr) * NC + k0 + lq*8);
#pragma unroll
            for (int fi = 0; fi < 4; fi++)
#pragma unroll
                for (int fj = 0; fj < 4; fj++)
                    acc[fi][fj] = MFMA16x16x32(a[fi], bb[fj], acc[fi][fj], 0, 0, 0);
        }
#pragma unroll
        for (int fi = 0; fi < 4; fi++)
#pragma unroll
            for (int fj = 0; fj < 4; fj++)
#pragma unroll
                for (int t = 0; t < 4; t++) {
                    int c = ti*64 + fi*16 + lq*4 + t;
                    int j = tj*64 + fj*16 + lr;
                    float v = acc[fi][fj][t] + bh[c];
                    int jt = j >> 6, ks = (j >> 5) & 1, lqd = (j >> 3) & 3, e = j & 7;
                    int ct = c >> 4, crd = c & 15;
                    size_t off = ((((size_t)(b*64 + jt)*32 + ct)*2 + ks)*64 + (lqd*16 + crd))*8 + e;
                    hT[off] = (bf16)v;
                }
    }
}

// -------------------- kernel 3: fused attention -----------------------------
// grid (8, 64): blockIdx.x = b (XCD-affinity). KVBLK=128: per phase p
// {h(2p) loads, PV(2p), h(2p+1) loads, PV(2p+1), S(2p+2)+S(2p+3) -> nxt buf,
//  barrier}. 32 phases. l-sum accumulated in S phase from float exp values.
__global__ __launch_bounds__(512, 4) void k_attn(
    const bf16* __restrict__ fF, const bf16* __restrict__ gF,
    const bf16* __restrict__ hT, const float* __restrict__ x,
    const float* __restrict__ gammap, float* __restrict__ out)
{
    __shared__ alignas(16) bf16 Pl[2][2][4][2][64][8];   // 32 KB: [buf][slot]...
    __shared__ float lpart[4][2][16];
    __shared__ alignas(16) float linv[64];

    int b  = blockIdx.x;
    int i0 = blockIdx.y * 64;
    int w = threadIdx.x >> 6, l = threadIdx.x & 63;
    int lr = l & 15, lq = l >> 4;

    float gamma = *gammap;
    int fi_s = w >> 1;     // i-subtile this wave computes in S
    int ks_s = w & 1;      // j32-block (PV k-block) this wave computes

    bf16* Pf = &Pl[0][0][0][0][0][0];
    // S-output write offset (elems) for fj=0; fj=1 adds 256.
    int wrA = ((fi_s*2 + ks_s)*64 + (lq >> 1)*16 + lr)*8 + (lq & 1)*4;

    // g B-fragments, hoisted (2 channel-halves)
    const bf16* gbase = gF + ((size_t)(b*256 + (i0 >> 4) + fi_s)*2)*512 + (size_t)l*8;
    bf16x8 bg0 = *(const bf16x8*)(gbase);
    bf16x8 bg1 = *(const bf16x8*)(gbase + 512);

    const bf16* fb0 = fF + (size_t)b*256*2*512 + (size_t)l*8;
    const bf16* hb0 = hT + (size_t)b*64*32*2*512 + (size_t)(w*4)*2*512 + (size_t)l*8;

    f32x4 oacc[4][4] = {};
    float lsum = 0.f;

    // ---- S for j-tile jn -> Pl[buf][slot]; always counted in lsum ----
#define S_STEP(jn, buf, slot)                                                  \
    {                                                                          \
        const bf16* fb = fb0 + (size_t)((jn)*4 + ks_s*2)*1024;                 \
        bf16x8 af00 = *(const bf16x8*)(fb);                                    \
        bf16x8 af01 = *(const bf16x8*)(fb + 512);                              \
        bf16x8 af10 = *(const bf16x8*)(fb + 1024);                             \
        bf16x8 af11 = *(const bf16x8*)(fb + 1536);                             \
        f32x4 s0 = {}, s1 = {};                                                \
        s0 = MFMA16x16x32(af00, bg0, s0, 0, 0, 0);                             \
        s0 = MFMA16x16x32(af01, bg1, s0, 0, 0, 0);                             \
        s1 = MFMA16x16x32(af10, bg0, s1, 0, 0, 0);                             \
        s1 = MFMA16x16x32(af11, bg1, s1, 0, 0, 0);                             \
        bf16x4 p0, p1;                                                         \
        _Pragma("unroll")                                                      \
        for (int t = 0; t < 4; t++) {                                          \
            float e0 = __expf(s0[t]), e1 = __expf(s1[t]);                      \
            lsum += e0 + e1;                                                   \
            p0[t] = (bf16)e0;                                                  \
            p1[t] = (bf16)e1;                                                  \
        }                                                                      \
        *(bf16x4*)(Pf + ((buf)*2 + (slot))*4096 + wrA)       = p0;             \
        *(bf16x4*)(Pf + ((buf)*2 + (slot))*4096 + wrA + 256) = p1;             \
    }

    // ---- PV for j-tile jt from Pl[buf][slot] ----
#define PV_STEP(jt, buf, slot)                                                 \
    {                                                                          \
        const bf16* hb = hb0 + (size_t)(jt) * 32768;                           \
        bf16x8 bh[4][2];                                                       \
        _Pragma("unroll")                                                      \
        for (int fc = 0; fc < 4; fc++) {                                       \
            bh[fc][0] = *(const bf16x8*)(hb + (fc*2 + 0)*512);                 \
            bh[fc][1] = *(const bf16x8*)(hb + (fc*2 + 1)*512);                 \
        }                                                                      \
        const bf16* Pr = Pf + ((buf)*2 + (slot))*4096 + l*8;                   \
        __builtin_amdgcn_s_setprio(1);                                         \
        _Pragma("unroll")                                                      \
        for (int fi = 0; fi < 4; fi++) {                                       \
            bf16x8 ap0 = *(const bf16x8*)(Pr + (fi*2 + 0)*512);                \
            bf16x8 ap1 = *(const bf16x8*)(Pr + (fi*2 + 1)*512);                \
            _Pragma("unroll")                                                  \
            for (int fc = 0; fc < 4; fc++) {                                   \
                oacc[fi][fc] = MFMA16x16x32(ap0, bh[fc][0], oacc[fi][fc], 0, 0, 0); \
                oacc[fi][fc] = MFMA16x16x32(ap1, bh[fc][1], oacc[fi][fc], 0, 0, 0); \
            }                                                                  \
        }                                                                      \
        __builtin_amdgcn_s_setprio(0);                                         \
    }

    // prologue: S(0), S(1) -> buf 0
    S_STEP(0, 0, 0)
    S_STEP(1, 0, 1)
    __syncthreads();

    for (int p = 0; p < 32; p++) {
        int cur = p & 1, nxt = cur ^ 1;

        PV_STEP(2*p,     cur, 0)
        PV_STEP(2*p + 1, cur, 1)

        if (p < 31) {
            S_STEP(2*p + 2, nxt, 0)
            S_STEP(2*p + 3, nxt, 1)
        }
        __syncthreads();
    }
#undef S_STEP
#undef PV_STEP

    // ---- l reduction: per-wave partials -> LDS -> linv ----
    lsum += __shfl_xor(lsum, 16, 64);
    lsum += __shfl_xor(lsum, 32, 64);
    if (lq == 0) lpart[fi_s][ks_s][lr] = lsum;
    __syncthreads();
    if (threadIdx.x < 64) {
        int i = threadIdx.x;
        linv[i] = 1.0f / (lpart[i >> 4][0][i & 15] + lpart[i >> 4][1][i & 15]);
    }
    __syncthreads();

    // ---- epilogue: out = gamma * O/l + x ----
    int cw = w * 64;
    const float* xb = x + (size_t)b * NC * NN;
    float* ob = out + (size_t)b * NC * NN;
#pragma unroll
    for (int fi = 0; fi < 4; fi++) {
        f32x4 li = *(const f32x4*)&linv[fi*16 + lq*4];
#pragma unroll
        for (int fc = 0; fc < 4; fc++) {
            int c = cw + fc*16 + lr;
            size_t base = (size_t)c * NN + i0 + fi*16 + lq*4;
            float4 xv = *(const float4*)(xb + base);
            float4 ov;
            ov.x = gamma * oacc[fi][fc][0] * li[0] + xv.x;
            ov.y = gamma * oacc[fi][fc][1] * li[1] + xv.y;
            ov.z = gamma * oacc[fi][fc][2] * li[2] + xv.z;
            ov.w = gamma * oacc[fi][fc][3] * li[3] + xv.w;
            *(float4*)(ob + base) = ov;
        }
    }
}

// -------------------- launcher ----------------------------------------------
extern "C" void kernel_launch(void* const* d_in, const int* in_sizes, int n_in,
                              void* d_out, int out_size, void* d_ws, size_t ws_size,
                              hipStream_t stream)
{
    const float* x     = (const float*)d_in[0];
    const float* Wf    = (const float*)d_in[1];
    const float* bf_   = (const float*)d_in[2];
    const float* Wg    = (const float*)d_in[3];
    const float* bg_   = (const float*)d_in[4];
    const float* Wh    = (const float*)d_in[5];
    const float* bh_   = (const float*)d_in[6];
    const float* gamma = (const float*)d_in[7];
    float* out = (float*)d_out;

    char* ws = (char*)d_ws;
    bf16*  xT  = (bf16*)(ws);
    bf16*  hT  = (bf16*)(ws + 33554432);
    bf16*  fF  = (bf16*)(ws + 67108864);
    bf16*  gF  = (bf16*)(ws + 71303168);
    bf16*  Wfg = (bf16*)(ws + 75497472);
    bf16*  Whb = (bf16*)(ws + 75628544);
    float* bfg = (float*)(ws + 76152832);

    k_wprep<<<dim3(1024), dim3(256), 0, stream>>>(Wf, bf_, Wg, bg_, Wh, Wfg, Whb, bfg);
    k_transpose<<<dim3(8, 64, 8), dim3(256), 0, stream>>>(x, xT);
    k_proj<<<dim3(8, 160), dim3(256), 0, stream>>>(xT, Wfg, bfg, Whb, bh_, fF, gF, hT);
    k_attn<<<dim3(8, 64), dim3(512), 0, stream>>>(fF, gF, hT, x, gamma, out);
}